// Round 4
// baseline (795.296 us; speedup 1.0000x reference)
//
#include <hip/hip_runtime.h>
#include <hip/hip_cooperative_groups.h>

namespace cg = cooperative_groups;

// KGE graph encoder, pruned to the backward cone of the 64 CLS nodes.
// R4: the whole pipeline is ONE cooperative kernel (256 blocks x 256 thr),
// grid.sync() between phases (kills 13 launch boundaries). int4-vectorized
// edge scans; 128-thread per-node phases run as 2 sub-blocks per block.

#define NN   50000
#define NE   800000
#define NR   500
#define HH   8
#define DD   16
#define HIDD 128
#define BB   64

#define NBLK 256
#define TPB  256
#define PER  3128        // ceil(NE/NBLK)=3125 -> %4==0; 256*3128 >= NE

#define MAXE2 16384
#define MAXS1 16448
#define MAXE1 262144
#define MAXS0 50000

// counters: [0]=cntS1 [1]=cntS0 [2]=cntE2 [3]=cntE1

struct KParams {
    const float *ent_table, *rel_table, *W_ent, *W_rel, *attn_l, *attn_r, *attn_e;
    const int *ent_ids, *rel_ids, *src, *dst, *goffs;
    float* out;
    float *rproj, *ee;
    int *slot2, *slot1, *slot0, *nodesS1, *nodesS0, *e2list, *e1list, *counters;
    int *eseg, *nseg, *ecnt, *ncnt, *ebase, *nbase;
    int *deg2, *rp2, *cur2, *deg1, *rp1, *cur1, *csr2, *csr1;
    float *feat0, *el0, *er0, *feat1, *el1, *er1;
};

__device__ int block_scan_counts(const int* cnts, int nblk, int* bases, int offset,
                                 int* part) {
    int t = threadIdx.x;
    int per = (nblk + 255) / 256;
    int s = 0;
    for (int j = 0; j < per; j++) { int i = t * per + j; if (i < nblk) s += cnts[i]; }
    part[t] = s;
    __syncthreads();
    for (int d = 1; d < 256; d <<= 1) {
        int v = (t >= d) ? part[t - d] : 0;
        __syncthreads();
        part[t] += v;
        __syncthreads();
    }
    int run = ((t == 0) ? 0 : part[t - 1]) + offset;
    for (int j = 0; j < per; j++) {
        int i = t * per + j;
        if (i < nblk) { bases[i] = run; run += cnts[i]; }
    }
    int tot = part[255];
    __syncthreads();
    return tot;
}

__device__ void excl_scan_glob(const int* deg, int n, int* rp, int* part) {
    int t = threadIdx.x;
    int per = (n + 255) / 256;
    int s = 0;
    for (int j = 0; j < per; j++) { int i = t * per + j; if (i < n) s += deg[i]; }
    part[t] = s;
    __syncthreads();
    for (int d = 1; d < 256; d <<= 1) {
        int v = (t >= d) ? part[t - d] : 0;
        __syncthreads();
        part[t] += v;
        __syncthreads();
    }
    int run = (t == 0) ? 0 : part[t - 1];
    for (int j = 0; j < per; j++) {
        int i = t * per + j;
        if (i < n) { rp[i] = run; run += deg[i]; }
    }
    if (t == 255) rp[n] = part[255];
    __syncthreads();
}

__global__ void __launch_bounds__(TPB, 1) k_all(KParams P) {
    cg::grid_group grid = cg::this_grid();
    const int b = blockIdx.x, t = threadIdx.x;
    const int gtid = b * TPB + t, gstride = NBLK * TPB;

    __shared__ int sh_cE, sh_cN;
    __shared__ int sh_part[256];
    __shared__ float sh_rows[2][8][HIDD];    // 8 KB, reused across phases

    const float* ee0 = P.ee;
    const float* ee1 = P.ee + NR * HH;
    const float* rproj0 = P.rproj;
    const float* rproj1 = P.rproj + (size_t)NR * HIDD;
    const float* W_ent1 = P.W_ent + HIDD * HIDD;
    const float* attn_l1 = P.attn_l + HH * DD;
    const float* attn_r1 = P.attn_r + HH * DD;

    // int4 edge scan over this block's range; appends to private segments.
    auto scan = [&](const int* slotHit, int* slotNew) {
        if (t == 0) { sh_cE = 0; sh_cN = 0; }
        __syncthreads();
        int lo = b * PER;
        int hi = lo + PER; if (hi > NE) hi = NE;
        int* es = P.eseg + (size_t)b * PER;
        int* ns = P.nseg + (size_t)b * PER;
        const int4* dst4 = (const int4*)(P.dst + lo);
        int n4 = (hi - lo) >> 2;
        for (int q = t; q < n4; q += TPB) {
            int4 d4 = dst4[q];
            int eb = lo + q * 4;
            #pragma unroll
            for (int c = 0; c < 4; c++) {
                int d = (&d4.x)[c];
                if (slotHit[d] >= 0) {
                    int pos = atomicAdd(&sh_cE, 1);
                    es[pos] = eb + c;
                    int s = P.src[eb + c];
                    if (atomicCAS(&slotNew[s], -1, -2) == -1) {
                        int pp = atomicAdd(&sh_cN, 1);
                        ns[pp] = s;
                    }
                }
            }
        }
        __syncthreads();
        if (t == 0) { P.ecnt[b] = sh_cE; P.ncnt[b] = sh_cN; }
    };

    // ---- P0: init membership maps + counters
    for (int n = gtid; n < NN; n += gstride) {
        P.slot2[n] = -1; P.slot1[n] = -1; P.slot0[n] = -1;
    }
    if (gtid < 8) P.counters[gtid] = 0;
    grid.sync();

    // ---- P1: seed CLS nodes
    if (b == 0 && t < BB) {
        int n = P.goffs[t];
        P.slot2[n] = t;
        P.slot1[n] = -2;
        P.nodesS1[t] = n;
    }
    grid.sync();

    // ---- P2: scan2 (edges into CLS set) + rel projection (independent)
    scan(P.slot2, P.slot1);
    {
        int sb = t >> 7, tt = t & 127;
        int vg = NBLK * 2;
        float (*rows)[HIDD] = sh_rows[sb];
        int iters = (2 * NR + vg - 1) / vg;
        for (int it = 0; it < iters; it++) {
            int vb = b * 2 + sb + it * vg;
            bool act = vb < 2 * NR;
            int l = act ? vb / NR : 0, r = act ? vb % NR : 0;
            if (act) rows[0][tt] = P.rel_table[r * HIDD + tt];
            __syncthreads();
            float acc = 0.f;
            if (act) {
                const float* W = P.W_rel + l * HIDD * HIDD;
                for (int j = 0; j < HIDD; j++) acc += rows[0][j] * W[j * HIDD + tt];
                P.rproj[(size_t)vb * HIDD + tt] = acc;
            }
            __syncthreads();
            if (act) rows[1][tt] = acc;
            __syncthreads();
            if (act && tt < HH) {
                float s = 0.f;
                for (int d = 0; d < DD; d++)
                    s += rows[1][tt * DD + d] * P.attn_e[(l * HH + tt) * DD + d];
                P.ee[vb * HH + tt] = s;
            }
            __syncthreads();
        }
    }
    grid.sync();

    // ---- P3: prefix over scan2 counts; CLS slots 0..63 of S1/S0
    if (b == 0) {
        int totE = block_scan_counts(P.ecnt, NBLK, P.ebase, 0, sh_part);
        int totN = block_scan_counts(P.ncnt, NBLK, P.nbase, BB, sh_part);
        if (t == 0) {
            P.counters[2] = min(totE, MAXE2);
            int s1 = min(BB + totN, MAXS1);
            P.counters[0] = s1;
            P.counters[1] = s1;
        }
        if (t < BB) {
            int n = P.nodesS1[t];
            P.slot1[n] = t;
            P.slot0[n] = t;
            P.nodesS0[t] = n;
        }
    }
    grid.sync();

    // ---- P4: compact2 + zero deg2
    {
        int ce = P.ecnt[b], cn = P.ncnt[b], be = P.ebase[b], bn = P.nbase[b];
        const int* es = P.eseg + (size_t)b * PER;
        const int* ns = P.nseg + (size_t)b * PER;
        for (int i = t; i < ce; i += TPB) {
            int g = be + i; if (g < MAXE2) P.e2list[g] = es[i];
        }
        for (int i = t; i < cn; i += TPB) {
            int idx = bn + i;
            if (idx < MAXS1) {
                int n = ns[i];
                P.nodesS1[idx] = n;
                P.slot1[n] = idx;
                P.slot0[n] = idx;
                P.nodesS0[idx] = n;
            }
        }
        if (b == 0) for (int i = t; i < BB; i += TPB) P.deg2[i] = 0;
    }
    grid.sync();

    // ---- P5: scan1 (edges into S1), reusing segments
    scan(P.slot1, P.slot0);
    grid.sync();

    // ---- P6: prefix over scan1 counts
    if (b == 0) {
        int s0 = P.counters[1];
        int totE = block_scan_counts(P.ecnt, NBLK, P.ebase, 0, sh_part);
        int totN = block_scan_counts(P.ncnt, NBLK, P.nbase, s0, sh_part);
        if (t == 0) {
            P.counters[3] = min(totE, MAXE1);
            P.counters[1] = min(s0 + totN, MAXS0);
        }
    }
    grid.sync();

    // ---- P7: compact1 + zero deg1
    {
        int ce = P.ecnt[b], cn = P.ncnt[b], be = P.ebase[b], bn = P.nbase[b];
        const int* es = P.eseg + (size_t)b * PER;
        const int* ns = P.nseg + (size_t)b * PER;
        for (int i = t; i < ce; i += TPB) {
            int g = be + i; if (g < MAXE1) P.e1list[g] = es[i];
        }
        for (int i = t; i < cn; i += TPB) {
            int idx = bn + i;
            if (idx < MAXS0) {
                int n = ns[i];
                P.slot0[n] = idx;
                P.nodesS0[idx] = n;
            }
        }
        int cnt1 = P.counters[0];
        for (int i = gtid; i < cnt1; i += gstride) P.deg1[i] = 0;
    }
    grid.sync();

    // ---- P8: degree histograms + feat0/el0/er0 (independent of CSR)
    {
        int c2 = P.counters[2], c1 = P.counters[3];
        for (int k = gtid; k < c2; k += gstride)
            atomicAdd(&P.deg2[P.slot2[P.dst[P.e2list[k]]]], 1);
        for (int k = gtid; k < c1; k += gstride)
            atomicAdd(&P.deg1[P.slot1[P.dst[P.e1list[k]]]], 1);
    }
    {
        int cnt = P.counters[1];
        int sb = t >> 7, tt = t & 127;
        int vg = NBLK * 2;
        float (*rows)[HIDD] = sh_rows[sb];
        int nT = (cnt + 7) / 8;
        int iters = (nT + vg - 1) / vg;
        for (int it = 0; it < iters; it++) {
            int tile = b * 2 + sb + it * vg;
            bool act = tile < nT;
            int k0 = tile * 8;
            #pragma unroll
            for (int m = 0; m < 8; m++) {
                int k = k0 + m;
                int n = P.nodesS0[(act && k < cnt) ? k : 0];
                rows[m][tt] = P.ent_table[(size_t)P.ent_ids[n] * HIDD + tt];
            }
            __syncthreads();
            float acc[8];
            #pragma unroll
            for (int m = 0; m < 8; m++) acc[m] = 0.f;
            if (act) {
                for (int j = 0; j < HIDD; j++) {
                    float w = P.W_ent[j * HIDD + tt];
                    #pragma unroll
                    for (int m = 0; m < 8; m++) acc[m] += rows[m][j] * w;
                }
            }
            __syncthreads();
            #pragma unroll
            for (int m = 0; m < 8; m++) {
                int k = k0 + m;
                if (act && k < cnt) P.feat0[(size_t)k * HIDD + tt] = acc[m];
                rows[m][tt] = acc[m];
            }
            __syncthreads();
            {
                int m = tt >> 4, idx = tt & 15, h = idx >> 1, isR = idx & 1;
                int k = k0 + m;
                if (act && k < cnt) {
                    const float* av = (isR ? P.attn_r : P.attn_l) + h * DD;
                    float s = 0.f;
                    for (int d = 0; d < DD; d++) s += rows[m][h * DD + d] * av[d];
                    if (isR) P.er0[k * HH + h] = s; else P.el0[k * HH + h] = s;
                }
            }
            __syncthreads();
        }
    }
    grid.sync();

    // ---- P9: rowptrs from degrees
    if (b == 0) {
        int cnt1 = P.counters[0];
        excl_scan_glob(P.deg2, BB, P.rp2, sh_part);
        excl_scan_glob(P.deg1, cnt1, P.rp1, sh_part);
        for (int i = t; i < BB; i += TPB) P.cur2[i] = P.rp2[i];
        for (int i = t; i < cnt1; i += TPB) P.cur1[i] = P.rp1[i];
    }
    grid.sync();

    // ---- P10: scatter edges into CSR
    {
        int c2 = P.counters[2], c1 = P.counters[3];
        for (int k = gtid; k < c2; k += gstride) {
            int e = P.e2list[k];
            int pos = atomicAdd(&P.cur2[P.slot2[P.dst[e]]], 1);
            if (pos < MAXE2) P.csr2[pos] = e;
        }
        for (int k = gtid; k < c1; k += gstride) {
            int e = P.e1list[k];
            int pos = atomicAdd(&P.cur1[P.slot1[P.dst[e]]], 1);
            if (pos < MAXE1) P.csr1[pos] = e;
        }
    }
    grid.sync();

    // ---- P11: layer 1 (softmax + aggregate + project), one node per sub-block
    {
        int cnt1 = P.counters[0];
        int sb = t >> 7, tt = t & 127, h = tt >> 4;
        int vg = NBLK * 2;
        float* row = (float*)sh_rows[sb];
        float* f2  = ((float*)sh_rows[sb]) + HIDD;
        int iters = (cnt1 + vg - 1) / vg;
        for (int it = 0; it < iters; it++) {
            int k = b * 2 + sb + it * vg;
            bool act = k < cnt1;
            int lo = 0, hi = 0;
            float er_k = 0.f;
            if (act) { lo = P.rp1[k]; hi = P.rp1[k + 1]; er_k = P.er0[k * HH + h]; }
            float accv = 0.f, sumex = 0.f;
            for (int i = lo; i < hi; i++) {
                int e = P.csr1[i];
                int ks = P.slot0[P.src[e]];
                int rid = P.rel_ids[e];
                float sc = P.el0[ks * HH + h] + er_k + ee0[rid * HH + h];
                sc = sc >= 0.f ? sc : 0.2f * sc;
                float ex = __expf(sc);
                sumex += ex;
                accv += ex * (P.feat0[(size_t)ks * HIDD + tt] + rproj0[rid * HIDD + tt]);
            }
            if (act) row[tt] = (hi > lo) ? accv / sumex : 0.f;
            __syncthreads();
            float f = 0.f;
            if (act) {
                for (int j = 0; j < HIDD; j++) f += row[j] * W_ent1[j * HIDD + tt];
                P.feat1[(size_t)k * HIDD + tt] = f;
                f2[tt] = f;
            }
            __syncthreads();
            if (act) {
                if (tt < HH) {
                    float s = 0.f;
                    for (int d = 0; d < DD; d++) s += f2[tt * DD + d] * attn_l1[tt * DD + d];
                    P.el1[k * HH + tt] = s;
                } else if (tt < 2 * HH) {
                    int hh = tt - HH;
                    float s = 0.f;
                    for (int d = 0; d < DD; d++) s += f2[hh * DD + d] * attn_r1[hh * DD + d];
                    P.er1[k * HH + hh] = s;
                }
            }
            __syncthreads();
        }
    }
    grid.sync();

    // ---- P12: layer 2, one CLS node per sub-block, direct output
    {
        int sb = t >> 7, tt = t & 127, h = tt >> 4;
        int vb = b * 2 + sb;
        if (vb < BB) {
            int lo = P.rp2[vb], hi = P.rp2[vb + 1];
            float er_g = P.er1[vb * HH + h];
            float accv = 0.f, sumex = 0.f;
            for (int i = lo; i < hi; i++) {
                int e = P.csr2[i];
                int ks = P.slot1[P.src[e]];
                int rid = P.rel_ids[e];
                float sc = P.el1[ks * HH + h] + er_g + ee1[rid * HH + h];
                sc = sc >= 0.f ? sc : 0.2f * sc;
                float ex = __expf(sc);
                sumex += ex;
                accv += ex * (P.feat1[(size_t)ks * HIDD + tt] + rproj1[rid * HIDD + tt]);
            }
            P.out[vb * HIDD + tt] = (hi > lo) ? accv / sumex : 0.f;
        }
    }
}

extern "C" void kernel_launch(void* const* d_in, const int* in_sizes, int n_in,
                              void* d_out, int out_size, void* d_ws, size_t ws_size,
                              hipStream_t stream) {
    KParams prm;
    prm.ent_table = (const float*)d_in[0];
    prm.rel_table = (const float*)d_in[1];
    prm.W_ent     = (const float*)d_in[2];
    prm.W_rel     = (const float*)d_in[3];
    prm.attn_l    = (const float*)d_in[4];
    prm.attn_r    = (const float*)d_in[5];
    prm.attn_e    = (const float*)d_in[6];
    prm.ent_ids   = (const int*)d_in[7];
    prm.rel_ids   = (const int*)d_in[8];
    prm.src       = (const int*)d_in[9];
    prm.dst       = (const int*)d_in[10];
    prm.goffs     = (const int*)d_in[11];
    prm.out       = (float*)d_out;

    char* p = (char*)d_ws;
    auto alloc = [&](size_t nbytes) {
        void* q = (void*)p;
        p += (nbytes + 255) & ~(size_t)255;
        return q;
    };
    prm.rproj   = (float*)alloc((size_t)2 * NR * HIDD * 4);
    prm.ee      = (float*)alloc((size_t)2 * NR * HH * 4);
    prm.slot2   = (int*)alloc((size_t)NN * 4);
    prm.slot1   = (int*)alloc((size_t)NN * 4);
    prm.slot0   = (int*)alloc((size_t)NN * 4);
    prm.nodesS1 = (int*)alloc((size_t)MAXS1 * 4);
    prm.nodesS0 = (int*)alloc((size_t)MAXS0 * 4);
    prm.e2list  = (int*)alloc((size_t)MAXE2 * 4);
    prm.e1list  = (int*)alloc((size_t)MAXE1 * 4);
    prm.counters= (int*)alloc(8 * 4);
    prm.eseg    = (int*)alloc((size_t)NBLK * PER * 4);
    prm.nseg    = (int*)alloc((size_t)NBLK * PER * 4);
    prm.ecnt    = (int*)alloc((size_t)NBLK * 4);
    prm.ncnt    = (int*)alloc((size_t)NBLK * 4);
    prm.ebase   = (int*)alloc((size_t)NBLK * 4);
    prm.nbase   = (int*)alloc((size_t)NBLK * 4);
    prm.deg2    = (int*)alloc((size_t)BB * 4);
    prm.rp2     = (int*)alloc((size_t)(BB + 1) * 4);
    prm.cur2    = (int*)alloc((size_t)BB * 4);
    prm.deg1    = (int*)alloc((size_t)MAXS1 * 4);
    prm.rp1     = (int*)alloc((size_t)(MAXS1 + 1) * 4);
    prm.cur1    = (int*)alloc((size_t)MAXS1 * 4);
    prm.csr2    = (int*)alloc((size_t)MAXE2 * 4);
    prm.csr1    = (int*)alloc((size_t)MAXE1 * 4);
    prm.feat0   = (float*)alloc((size_t)MAXS0 * HIDD * 4);
    prm.el0     = (float*)alloc((size_t)MAXS0 * HH * 4);
    prm.er0     = (float*)alloc((size_t)MAXS0 * HH * 4);
    prm.feat1   = (float*)alloc((size_t)MAXS1 * HIDD * 4);
    prm.el1     = (float*)alloc((size_t)MAXS1 * HH * 4);
    prm.er1     = (float*)alloc((size_t)MAXS1 * HH * 4);

    void* args[] = { (void*)&prm };
    hipLaunchCooperativeKernel(reinterpret_cast<void*>(k_all),
                               dim3(NBLK), dim3(TPB), args, 0, stream);
}

// Round 5
// 429.909 us; speedup vs baseline: 1.8499x; 1.8499x over previous
//
#include <hip/hip_runtime.h>

// KGE graph encoder, pruned to the backward cone of the 64 CLS nodes.
// R5: R3 multi-kernel structure (cooperative grid.sync was ~30us/sync -> R4
// regressed). 10 launches: deg histograms folded into scans, rowptr/cur into
// the 1-block prefix kernels, CSR scatter into compacts (private segments
// read directly, edge lists never materialized). CLS membership via 6-step
// LDS binary search over sorted goffs (no slot2 array, no 800K gathers).

#define NN   50000
#define NE   800000
#define NR   500
#define HH   8
#define DD   16
#define HIDD 128
#define BB   64

#define GRIDS 1024
#define PER   784       // GRIDS*PER >= NE, PER%4==0

#define MAXS1 16448
#define MAXE1 262144
#define MAXS0 50000
#define MAXE2 16384

// counters: [0]=cntS1 [1]=cntS0

__global__ void k_init(int* slot1, int* slot0, int* counters, int* deg2, int* deg1) {
    int i = blockIdx.x * blockDim.x + threadIdx.x;
    int stride = gridDim.x * blockDim.x;
    for (int n = i; n < NN; n += stride) { slot1[n] = -1; slot0[n] = -1; }
    for (int n = i; n < MAXS1; n += stride) deg1[n] = 0;
    if (i < BB) deg2[i] = 0;
    if (i < 8) counters[i] = 0;
}

// scan2: edges with dst == some CLS node (binary search in goffs). Appends
// edge to this block's private segment, counts deg2[g], discovers S1 srcs
// (excluding CLS nodes) via CAS into slot1.
__global__ void k_scan2(const int* __restrict__ src, const int* __restrict__ dst,
                        const int* __restrict__ goffs, int* __restrict__ slot1,
                        int* eseg, int* ecnt, int* nseg, int* ncnt, int* deg2) {
    __shared__ int sgo[BB];
    __shared__ int cE, cN;
    int t = threadIdx.x, b = blockIdx.x;
    if (t < BB) sgo[t] = goffs[t];
    if (t == 0) { cE = 0; cN = 0; }
    __syncthreads();
    auto findg = [&](int d) -> int {
        int lo = 0, hi = BB - 1;
        #pragma unroll
        for (int s = 0; s < 6; s++) {
            int mid = (lo + hi) >> 1;
            if (sgo[mid] < d) lo = mid + 1; else hi = mid;
        }
        return (sgo[lo] == d) ? lo : -1;
    };
    int lo = b * PER;
    int hi = lo + PER; if (hi > NE) hi = NE;
    if (hi > lo) {
        int* es = eseg + (size_t)b * PER;
        int* ns = nseg + (size_t)b * PER;
        const int4* dst4 = (const int4*)(dst + lo);
        int n4 = (hi - lo) >> 2;
        for (int q = t; q < n4; q += blockDim.x) {
            int4 d4 = dst4[q];
            int eb = lo + q * 4;
            #pragma unroll
            for (int c = 0; c < 4; c++) {
                int d = (&d4.x)[c];
                int g = findg(d);
                if (g >= 0) {
                    int pos = atomicAdd(&cE, 1);
                    es[pos] = eb + c;
                    atomicAdd(&deg2[g], 1);
                    int s = src[eb + c];
                    if (findg(s) < 0 && atomicCAS(&slot1[s], -1, -2) == -1) {
                        int pp = atomicAdd(&cN, 1);
                        ns[pp] = s;
                    }
                }
            }
        }
    }
    __syncthreads();
    if (t == 0) { ecnt[b] = cE; ncnt[b] = cN; }
}

// exclusive scan over nblk counts; returns total (all threads)
__device__ int block_scan_counts(const int* cnts, int nblk, int* bases, int offset,
                                 int* part) {
    int t = threadIdx.x;
    int per = (nblk + 255) / 256;
    int s = 0;
    for (int j = 0; j < per; j++) { int i = t * per + j; if (i < nblk) s += cnts[i]; }
    part[t] = s;
    __syncthreads();
    for (int d = 1; d < 256; d <<= 1) {
        int v = (t >= d) ? part[t - d] : 0;
        __syncthreads();
        part[t] += v;
        __syncthreads();
    }
    int run = ((t == 0) ? 0 : part[t - 1]) + offset;
    for (int j = 0; j < per; j++) {
        int i = t * per + j;
        if (i < nblk) { bases[i] = run; run += cnts[i]; }
    }
    int tot = part[255];
    __syncthreads();
    return tot;
}

__device__ void excl_scan_glob(const int* deg, int n, int* rp, int* part) {
    int t = threadIdx.x;
    int per = (n + 255) / 256;
    int s = 0;
    for (int j = 0; j < per; j++) { int i = t * per + j; if (i < n) s += deg[i]; }
    part[t] = s;
    __syncthreads();
    for (int d = 1; d < 256; d <<= 1) {
        int v = (t >= d) ? part[t - d] : 0;
        __syncthreads();
        part[t] += v;
        __syncthreads();
    }
    int run = (t == 0) ? 0 : part[t - 1];
    for (int j = 0; j < per; j++) {
        int i = t * per + j;
        if (i < n) { rp[i] = run; run += deg[i]; }
    }
    if (t == 255) rp[n] = part[255];
    __syncthreads();
}

// 1 block: node-count prefix for scan2, CLS slot assignment, rp2/cur2.
__global__ void k_prefix2(const int* ncnt, int* nbase, int* counters,
                          const int* goffs, int* slot1, int* slot0, int* nodesS0,
                          const int* deg2, int* rp2, int* cur2) {
    __shared__ int part[256];
    int t = threadIdx.x;
    int totN = block_scan_counts(ncnt, GRIDS, nbase, BB, part);
    if (t == 0) {
        int s1 = BB + totN; if (s1 > MAXS1) s1 = MAXS1;
        counters[0] = s1;
        counters[1] = s1;
    }
    excl_scan_glob(deg2, BB, rp2, part);
    for (int i = t; i < BB; i += blockDim.x) cur2[i] = rp2[i];
    if (t < BB) {
        int n = goffs[t];
        slot1[n] = t;
        slot0[n] = t;
        nodesS0[t] = n;
    }
}

// compact2: assign slots to discovered S1 nodes; scatter this block's hit
// edges into csr2 (row = graph index of dst, via binary search).
__global__ void k_compact2(const int* eseg, const int* ecnt,
                           const int* nseg, const int* ncnt, const int* nbase,
                           const int* goffs, const int* dst,
                           int* slot1, int* slot0, int* nodesS0,
                           int* cur2, int* csr2) {
    __shared__ int sgo[BB];
    int t = threadIdx.x, b = blockIdx.x;
    if (t < BB) sgo[t] = goffs[t];
    __syncthreads();
    int ce = ecnt[b], cn = ncnt[b], bn = nbase[b];
    const int* es = eseg + (size_t)b * PER;
    const int* ns = nseg + (size_t)b * PER;
    for (int i = t; i < cn; i += blockDim.x) {
        int idx = bn + i;
        if (idx < MAXS1) {
            int n = ns[i];
            slot1[n] = idx;
            slot0[n] = idx;
            nodesS0[idx] = n;
        }
    }
    for (int i = t; i < ce; i += blockDim.x) {
        int e = es[i];
        int d = dst[e];
        int lo = 0, hi = BB - 1;
        #pragma unroll
        for (int s = 0; s < 6; s++) {
            int mid = (lo + hi) >> 1;
            if (sgo[mid] < d) lo = mid + 1; else hi = mid;
        }
        int pos = atomicAdd(&cur2[lo], 1);
        if (pos < MAXE2) csr2[pos] = e;
    }
}

// scan1: edges with slot1[dst]>=0; counts deg1, discovers S0 srcs via slot0.
__global__ void k_scan1(const int* __restrict__ src, const int* __restrict__ dst,
                        const int* __restrict__ slot1, int* __restrict__ slot0,
                        int* eseg, int* ecnt, int* nseg, int* ncnt, int* deg1) {
    __shared__ int cE, cN;
    int t = threadIdx.x, b = blockIdx.x;
    if (t == 0) { cE = 0; cN = 0; }
    __syncthreads();
    int lo = b * PER;
    int hi = lo + PER; if (hi > NE) hi = NE;
    if (hi > lo) {
        int* es = eseg + (size_t)b * PER;
        int* ns = nseg + (size_t)b * PER;
        const int4* dst4 = (const int4*)(dst + lo);
        int n4 = (hi - lo) >> 2;
        for (int q = t; q < n4; q += blockDim.x) {
            int4 d4 = dst4[q];
            int eb = lo + q * 4;
            #pragma unroll
            for (int c = 0; c < 4; c++) {
                int kd = slot1[(&d4.x)[c]];
                if (kd >= 0) {
                    int pos = atomicAdd(&cE, 1);
                    es[pos] = eb + c;
                    atomicAdd(&deg1[kd], 1);
                    int s = src[eb + c];
                    if (atomicCAS(&slot0[s], -1, -2) == -1) {
                        int pp = atomicAdd(&cN, 1);
                        ns[pp] = s;
                    }
                }
            }
        }
    }
    __syncthreads();
    if (t == 0) { ecnt[b] = cE; ncnt[b] = cN; }
}

// 1 block: node-count prefix for scan1, rp1/cur1.
__global__ void k_prefix1(const int* ncnt, int* nbase, int* counters,
                          const int* deg1, int* rp1, int* cur1) {
    __shared__ int part[256];
    int t = threadIdx.x;
    int s0 = counters[1];
    int cnt1 = counters[0];
    int totN = block_scan_counts(ncnt, GRIDS, nbase, s0, part);
    if (t == 0) {
        int v = s0 + totN; if (v > MAXS0) v = MAXS0;
        counters[1] = v;
    }
    excl_scan_glob(deg1, cnt1, rp1, part);
    for (int i = t; i < cnt1; i += blockDim.x) cur1[i] = rp1[i];
}

// compact1: assign slots to discovered S0 nodes; scatter hit edges into csr1.
__global__ void k_compact1(const int* eseg, const int* ecnt,
                           const int* nseg, const int* ncnt, const int* nbase,
                           const int* dst, const int* slot1,
                           int* slot0, int* nodesS0, int* cur1, int* csr1) {
    int t = threadIdx.x, b = blockIdx.x;
    int ce = ecnt[b], cn = ncnt[b], bn = nbase[b];
    const int* es = eseg + (size_t)b * PER;
    const int* ns = nseg + (size_t)b * PER;
    for (int i = t; i < cn; i += blockDim.x) {
        int idx = bn + i;
        if (idx < MAXS0) {
            int n = ns[i];
            slot0[n] = idx;
            nodesS0[idx] = n;
        }
    }
    for (int i = t; i < ce; i += blockDim.x) {
        int e = es[i];
        int kd = slot1[dst[e]];
        int pos = atomicAdd(&cur1[kd], 1);
        if (pos < MAXE1) csr1[pos] = e;
    }
}

// Fused: blocks [0, 2*NR) project rel_table (rproj, ee); remaining blocks
// compute feat0/el0/er0 for S0 nodes, 8 per tile (W_ent amortized).
#define FT 8
__global__ void k_relfeat0(const float* rel_table, const float* __restrict__ W_rel,
                           const float* attn_e, float* rproj, float* ee,
                           const int* nodesS0, const int* counters, const int* ent_ids,
                           const float* __restrict__ ent_table,
                           const float* __restrict__ W_ent,
                           const float* __restrict__ attn_l,
                           const float* __restrict__ attn_r,
                           float* feat0, float* el0, float* er0) {
    __shared__ float rows[FT][HIDD];
    int t = threadIdx.x;              // 0..127
    if (blockIdx.x < 2 * NR) {
        int l = blockIdx.x / NR, r = blockIdx.x % NR;
        rows[0][t] = rel_table[r * HIDD + t];
        __syncthreads();
        const float* W = W_rel + l * HIDD * HIDD;
        float acc = 0.f;
        for (int j = 0; j < HIDD; j++) acc += rows[0][j] * W[j * HIDD + t];
        rproj[(l * NR + r) * HIDD + t] = acc;
        rows[1][t] = acc;
        __syncthreads();
        if (t < HH) {
            float s = 0.f;
            for (int d = 0; d < DD; d++)
                s += rows[1][t * DD + d] * attn_e[(l * HH + t) * DD + d];
            ee[(l * NR + r) * HH + t] = s;
        }
        return;
    }
    int cnt = counters[1]; if (cnt > MAXS0) cnt = MAXS0;
    int tile0 = blockIdx.x - 2 * NR;
    int tstride = gridDim.x - 2 * NR;
    int nTiles = (cnt + FT - 1) / FT;
    for (int tile = tile0; tile < nTiles; tile += tstride) {
        int k0 = tile * FT;
        #pragma unroll
        for (int m = 0; m < FT; m++) {
            int k = k0 + m;
            int n = nodesS0[k < cnt ? k : 0];
            rows[m][t] = ent_table[(size_t)ent_ids[n] * HIDD + t];
        }
        __syncthreads();
        float acc[FT];
        #pragma unroll
        for (int m = 0; m < FT; m++) acc[m] = 0.f;
        for (int j = 0; j < HIDD; j++) {
            float w = W_ent[j * HIDD + t];
            #pragma unroll
            for (int m = 0; m < FT; m++) acc[m] += rows[m][j] * w;
        }
        __syncthreads();
        #pragma unroll
        for (int m = 0; m < FT; m++) {
            int k = k0 + m;
            if (k < cnt) feat0[(size_t)k * HIDD + t] = acc[m];
            rows[m][t] = acc[m];
        }
        __syncthreads();
        {   // 8 nodes x 8 heads x {el,er}
            int m = t >> 4, idx = t & 15, h = idx >> 1, isR = idx & 1;
            int k = k0 + m;
            if (k < cnt) {
                const float* av = (isR ? attn_r : attn_l) + h * DD;
                float s = 0.f;
                for (int d = 0; d < DD; d++) s += rows[m][h * DD + d] * av[d];
                if (isR) er0[k * HH + h] = s; else el0[k * HH + h] = s;
            }
        }
        __syncthreads();
    }
}

// Layer 1: one block per S1 node, no atomics.
__global__ void k_layer1(const int* counters, const int* rp1, const int* csr1,
                         const int* src, const int* rel_ids, const int* slot0,
                         const float* __restrict__ el0, const float* __restrict__ er0,
                         const float* __restrict__ ee0,
                         const float* __restrict__ feat0, const float* __restrict__ rproj0,
                         const float* __restrict__ W_ent1,
                         const float* attn_l1, const float* attn_r1,
                         float* feat1, float* el1, float* er1) {
    int cnt1 = counters[0];
    int t = threadIdx.x;              // 0..127
    int h = t >> 4;
    __shared__ float row[HIDD];
    __shared__ float f2[HIDD];
    for (int k = blockIdx.x; k < cnt1; k += gridDim.x) {
        int lo = rp1[k], hi = rp1[k + 1];
        float er_k = er0[k * HH + h];     // slot0 of an S1 node == its slot1
        float acc = 0.f, sumex = 0.f;
        for (int i = lo; i < hi; i++) {
            int e = csr1[i];
            int ks = slot0[src[e]];
            int rid = rel_ids[e];
            float sc = el0[ks * HH + h] + er_k + ee0[rid * HH + h];
            sc = sc >= 0.f ? sc : 0.2f * sc;
            float ex = __expf(sc);
            sumex += ex;
            acc += ex * (feat0[(size_t)ks * HIDD + t] + rproj0[rid * HIDD + t]);
        }
        row[t] = (hi > lo) ? acc / sumex : 0.f;
        __syncthreads();
        float f = 0.f;
        for (int j = 0; j < HIDD; j++) f += row[j] * W_ent1[j * HIDD + t];
        feat1[(size_t)k * HIDD + t] = f;
        f2[t] = f;
        __syncthreads();
        if (t < HH) {
            float s = 0.f;
            for (int d = 0; d < DD; d++) s += f2[t * DD + d] * attn_l1[t * DD + d];
            el1[k * HH + t] = s;
        } else if (t < 2 * HH) {
            int hh = t - HH;
            float s = 0.f;
            for (int d = 0; d < DD; d++) s += f2[hh * DD + d] * attn_r1[hh * DD + d];
            er1[k * HH + hh] = s;
        }
        __syncthreads();
    }
}

// Layer 2: one block per CLS node (graph), writes output directly.
__global__ void k_layer2(const int* rp2, const int* csr2,
                         const int* src, const int* rel_ids, const int* slot1,
                         const float* __restrict__ el1, const float* __restrict__ er1,
                         const float* __restrict__ ee1,
                         const float* __restrict__ feat1, const float* __restrict__ rproj1,
                         float* out) {
    int g = blockIdx.x;               // 0..63
    int t = threadIdx.x;              // 0..127
    int h = t >> 4;
    int lo = rp2[g], hi = rp2[g + 1];
    float er_g = er1[g * HH + h];     // CLS node g has slot1 == g
    float acc = 0.f, sumex = 0.f;
    for (int i = lo; i < hi; i++) {
        int e = csr2[i];
        int ks = slot1[src[e]];
        int rid = rel_ids[e];
        float sc = el1[ks * HH + h] + er_g + ee1[rid * HH + h];
        sc = sc >= 0.f ? sc : 0.2f * sc;
        float ex = __expf(sc);
        sumex += ex;
        acc += ex * (feat1[(size_t)ks * HIDD + t] + rproj1[rid * HIDD + t]);
    }
    out[g * HIDD + t] = (hi > lo) ? acc / sumex : 0.f;
}

extern "C" void kernel_launch(void* const* d_in, const int* in_sizes, int n_in,
                              void* d_out, int out_size, void* d_ws, size_t ws_size,
                              hipStream_t stream) {
    const float* ent_table = (const float*)d_in[0];
    const float* rel_table = (const float*)d_in[1];
    const float* W_ent     = (const float*)d_in[2];
    const float* W_rel     = (const float*)d_in[3];
    const float* attn_l    = (const float*)d_in[4];
    const float* attn_r    = (const float*)d_in[5];
    const float* attn_e    = (const float*)d_in[6];
    const int*   ent_ids   = (const int*)d_in[7];
    const int*   rel_ids   = (const int*)d_in[8];
    const int*   src       = (const int*)d_in[9];
    const int*   dst       = (const int*)d_in[10];
    const int*   goffs     = (const int*)d_in[11];
    float*       out       = (float*)d_out;

    char* p = (char*)d_ws;
    auto alloc = [&](size_t nbytes) {
        void* q = (void*)p;
        p += (nbytes + 255) & ~(size_t)255;
        return q;
    };
    float* rproj   = (float*)alloc((size_t)2 * NR * HIDD * 4);
    float* ee      = (float*)alloc((size_t)2 * NR * HH * 4);
    int*   slot1   = (int*)alloc((size_t)NN * 4);
    int*   slot0   = (int*)alloc((size_t)NN * 4);
    int*   nodesS0 = (int*)alloc((size_t)MAXS0 * 4);
    int*   counters= (int*)alloc(8 * 4);
    int*   eseg    = (int*)alloc((size_t)GRIDS * PER * 4);
    int*   nseg    = (int*)alloc((size_t)GRIDS * PER * 4);
    int*   ecnt    = (int*)alloc((size_t)GRIDS * 4);
    int*   ncnt    = (int*)alloc((size_t)GRIDS * 4);
    int*   nbase   = (int*)alloc((size_t)GRIDS * 4);
    int*   deg2    = (int*)alloc((size_t)BB * 4);
    int*   rp2     = (int*)alloc((size_t)(BB + 1) * 4);
    int*   cur2    = (int*)alloc((size_t)BB * 4);
    int*   deg1    = (int*)alloc((size_t)MAXS1 * 4);
    int*   rp1     = (int*)alloc((size_t)(MAXS1 + 1) * 4);
    int*   cur1    = (int*)alloc((size_t)MAXS1 * 4);
    int*   csr2    = (int*)alloc((size_t)MAXE2 * 4);
    int*   csr1    = (int*)alloc((size_t)MAXE1 * 4);
    float* feat0   = (float*)alloc((size_t)MAXS0 * HIDD * 4);
    float* el0     = (float*)alloc((size_t)MAXS0 * HH * 4);
    float* er0     = (float*)alloc((size_t)MAXS0 * HH * 4);
    float* feat1   = (float*)alloc((size_t)MAXS1 * HIDD * 4);
    float* el1     = (float*)alloc((size_t)MAXS1 * HH * 4);
    float* er1     = (float*)alloc((size_t)MAXS1 * HH * 4);

    const float* rproj0 = rproj;
    const float* rproj1 = rproj + (size_t)NR * HIDD;
    const float* ee0 = ee;
    const float* ee1 = ee + (size_t)NR * HH;
    const float* W_ent0 = W_ent;
    const float* W_ent1 = W_ent + HIDD * HIDD;
    const float* attn_l0 = attn_l, *attn_l1 = attn_l + HH * DD;
    const float* attn_r0 = attn_r, *attn_r1 = attn_r + HH * DD;

    hipLaunchKernelGGL(k_init, dim3(256), dim3(256), 0, stream,
                       slot1, slot0, counters, deg2, deg1);
    hipLaunchKernelGGL(k_scan2, dim3(GRIDS), dim3(256), 0, stream,
                       src, dst, goffs, slot1, eseg, ecnt, nseg, ncnt, deg2);
    hipLaunchKernelGGL(k_prefix2, dim3(1), dim3(256), 0, stream,
                       ncnt, nbase, counters, goffs, slot1, slot0, nodesS0,
                       deg2, rp2, cur2);
    hipLaunchKernelGGL(k_compact2, dim3(GRIDS), dim3(256), 0, stream,
                       eseg, ecnt, nseg, ncnt, nbase, goffs, dst,
                       slot1, slot0, nodesS0, cur2, csr2);
    hipLaunchKernelGGL(k_scan1, dim3(GRIDS), dim3(256), 0, stream,
                       src, dst, slot1, slot0, eseg, ecnt, nseg, ncnt, deg1);
    hipLaunchKernelGGL(k_prefix1, dim3(1), dim3(256), 0, stream,
                       ncnt, nbase, counters, deg1, rp1, cur1);
    hipLaunchKernelGGL(k_compact1, dim3(GRIDS), dim3(256), 0, stream,
                       eseg, ecnt, nseg, ncnt, nbase, dst, slot1,
                       slot0, nodesS0, cur1, csr1);
    hipLaunchKernelGGL(k_relfeat0, dim3(2 * NR + 1024), dim3(HIDD), 0, stream,
                       rel_table, W_rel, attn_e, rproj, ee,
                       nodesS0, counters, ent_ids, ent_table, W_ent0,
                       attn_l0, attn_r0, feat0, el0, er0);
    hipLaunchKernelGGL(k_layer1, dim3(2048), dim3(HIDD), 0, stream,
                       counters, rp1, csr1, src, rel_ids, slot0,
                       el0, er0, ee0, feat0, rproj0, W_ent1,
                       attn_l1, attn_r1, feat1, el1, er1);
    hipLaunchKernelGGL(k_layer2, dim3(BB), dim3(HIDD), 0, stream,
                       rp2, csr2, src, rel_ids, slot1,
                       el1, er1, ee1, feat1, rproj1, out);
}